// Round 2
// baseline (780.704 us; speedup 1.0000x reference)
//
#include <hip/hip_runtime.h>

typedef __attribute__((ext_vector_type(8))) _Float16 half8;
typedef __attribute__((ext_vector_type(4))) float f32x4;

#define BN_EPS 1e-5f

__device__ __forceinline__ void async_copy16(const void* g, void* l) {
  __builtin_amdgcn_global_load_lds((const __attribute__((address_space(1))) void*)g,
                                   (__attribute__((address_space(3))) void*)l,
                                   16, 0, 0);
}

// ---------------- kernel 1: x (B,C,N) fp32 -> xT (B,N,C) fp16 ----------------
__global__ void k_transpose(const float* __restrict__ x, _Float16* __restrict__ xT) {
  __shared__ float tile[64][65];
  int n0 = blockIdx.x * 64, c0 = blockIdx.y * 64, b = blockIdx.z;
  const float* xb = x + (size_t)b * 512 * 4096;
  int t = threadIdx.x;
#pragma unroll
  for (int rep = 0; rep < 16; ++rep) {
    int idx = rep * 256 + t;
    int r = idx >> 6, cc = idx & 63;           // r: c-row, cc: n-col
    tile[r][cc] = xb[(size_t)(c0 + r) * 4096 + n0 + cc];
  }
  __syncthreads();
  _Float16* xTb = xT + (size_t)b * 4096 * 512;
#pragma unroll
  for (int rep = 0; rep < 16; ++rep) {
    int idx = rep * 256 + t;
    int r = idx >> 6, cc = idx & 63;           // r: n-row, cc: c-col
    xTb[(size_t)(n0 + r) * 512 + c0 + cc] = (_Float16)tile[cc][r];
  }
}

// ---------------- kernel 2: W_all (640x512) fp16 = [Wq; Wk; Wv] ----------------
__global__ void k_wall(const float* __restrict__ Wq, const float* __restrict__ Wk,
                       const float* __restrict__ Wv, _Float16* __restrict__ W_all) {
  int i = blockIdx.x * 256 + threadIdx.x;
  if (i >= 640 * 512) return;
  int m = i >> 9, c = i & 511;
  float v;
  if (m < 64) v = Wq[m * 512 + c];
  else if (m < 128) v = Wk[(m - 64) * 512 + c];
  else v = Wv[(m - 128) * 512 + c];
  W_all[i] = (_Float16)v;
}

// ---------------- kernel 3: proj GEMM: OUT(640 x 4096) = W_all @ x_b per batch ----------------
// epilogue: rows 0-63 -> q_buf(b,n,64)+bq ; 64-127 -> kT_buf(b,n,64)+bk ; 128-639 -> v_buf(b,vv,n) BN+ReLU
__global__ __launch_bounds__(256) void k_proj(
    const _Float16* __restrict__ W_all, const _Float16* __restrict__ xT,
    const float* __restrict__ bq, const float* __restrict__ bk,
    const float* __restrict__ gamma, const float* __restrict__ beta,
    const float* __restrict__ mean, const float* __restrict__ var,
    _Float16* __restrict__ q_buf, _Float16* __restrict__ kT_buf,
    _Float16* __restrict__ v_buf) {
  __shared__ __align__(16) _Float16 A_lds[128 * 32];  // [m][k]
  __shared__ __align__(16) _Float16 B_lds[128 * 32];  // [n][k] (k-contig)
  int nt = blockIdx.x, mt = blockIdx.y, b = blockIdx.z;
  int t = threadIdx.x, w = t >> 6, lane = t & 63;
  int quad = lane >> 4, l16 = lane & 15;
  int moff = (w & 1) * 64, noff = (w >> 1) * 64;

  f32x4 acc[4][4] = {};

  for (int kk = 0; kk < 16; ++kk) {
    int kc = kk * 32;
#pragma unroll
    for (int c = 0; c < 2; ++c) {
      int row = (w * 2 + c) * 16 + (lane >> 2);
      int kseg = (lane & 3) * 8;
      async_copy16(W_all + (size_t)(mt * 128 + row) * 512 + kc + kseg,
                   (char*)A_lds + (w * 2 + c) * 1024 + lane * 16);
      async_copy16(xT + ((size_t)b * 4096 + nt * 128 + row) * 512 + kc + kseg,
                   (char*)B_lds + (w * 2 + c) * 1024 + lane * 16);
    }
    __syncthreads();
    half8 a[4], bb[4];
#pragma unroll
    for (int mi = 0; mi < 4; ++mi)
      a[mi] = *(const half8*)&A_lds[(moff + 16 * mi + l16) * 32 + 8 * quad];
#pragma unroll
    for (int ni = 0; ni < 4; ++ni)
      bb[ni] = *(const half8*)&B_lds[(noff + 16 * ni + l16) * 32 + 8 * quad];
#pragma unroll
    for (int mi = 0; mi < 4; ++mi)
#pragma unroll
      for (int ni = 0; ni < 4; ++ni)
        acc[mi][ni] = __builtin_amdgcn_mfma_f32_16x16x32_f16(a[mi], bb[ni], acc[mi][ni], 0, 0, 0);
    __syncthreads();
  }

  size_t bN = (size_t)b * 4096;
#pragma unroll
  for (int mi = 0; mi < 4; ++mi) {
    int mbase = mt * 128 + moff + 16 * mi + 4 * quad;
#pragma unroll
    for (int ni = 0; ni < 4; ++ni) {
      int n = nt * 128 + noff + 16 * ni + l16;
#pragma unroll
      for (int i = 0; i < 4; ++i) {
        int m = mbase + i;
        float val = acc[mi][ni][i];
        if (m < 64) {
          q_buf[(bN + n) * 64 + m] = (_Float16)(val + bq[m]);
        } else if (m < 128) {
          kT_buf[(bN + n) * 64 + (m - 64)] = (_Float16)(val + bk[m - 64]);
        } else {
          int vv = m - 128;
          float sc = gamma[vv] * rsqrtf(var[vv] + BN_EPS);
          float sh = beta[vv] - mean[vv] * sc;
          float r = val * sc + sh;
          v_buf[((size_t)b * 512 + vv) * 4096 + n] = (_Float16)(r > 0.f ? r : 0.f);
        }
      }
    }
  }
}

// ---------------- kernel 4: flash attention ----------------
// per wg: batch b, 64 Q rows. wave w: S strip rows [16w,16w+16), O chunk V-cols [128w,128w+128)
__global__ __launch_bounds__(256) void k_flash(
    const _Float16* __restrict__ q_buf, const _Float16* __restrict__ kT_buf,
    const _Float16* __restrict__ v_buf, float* __restrict__ out) {
  __shared__ __align__(16) _Float16 P_lds[64 * 72];  // row stride 72 (pad, 16B-aligned)
  __shared__ float alpha_lds[64];
  __shared__ float l_lds[64];
  int b = blockIdx.y;
  int n0 = blockIdx.x * 64;
  int t = threadIdx.x, w = t >> 6, lane = t & 63, quad = lane >> 4, l16 = lane & 15;
  const _Float16* qb = q_buf + (size_t)b * 4096 * 64;
  const _Float16* kb = kT_buf + (size_t)b * 4096 * 64;
  const _Float16* vb = v_buf + (size_t)b * 512 * 4096;

  half8 aq[2];
#pragma unroll
  for (int s = 0; s < 2; ++s)
    aq[s] = *(const half8*)&qb[(size_t)(n0 + 16 * w + l16) * 64 + 32 * s + 8 * quad];

  f32x4 o[4][8] = {};
  float m_st[4], l_st[4];
#pragma unroll
  for (int i = 0; i < 4; ++i) { m_st[i] = -1e30f; l_st[i] = 0.f; }

#pragma unroll 1
  for (int it = 0; it < 64; ++it) {
    int m0 = it * 64;
    // ---- S = Q Kt for this wave's 16-row strip ----
    f32x4 sc[4];
#pragma unroll
    for (int ct = 0; ct < 4; ++ct) {
      f32x4 s_acc = {0.f, 0.f, 0.f, 0.f};
#pragma unroll
      for (int s = 0; s < 2; ++s) {
        half8 bk_ = *(const half8*)&kb[(size_t)(m0 + 16 * ct + l16) * 64 + 32 * s + 8 * quad];
        s_acc = __builtin_amdgcn_mfma_f32_16x16x32_f16(aq[s], bk_, s_acc, 0, 0, 0);
      }
      sc[ct] = s_acc;
    }
    // ---- online softmax (rows 4*quad+i of strip) ----
    float alpha[4], p[4][4];
#pragma unroll
    for (int i = 0; i < 4; ++i) {
      float mxi = fmaxf(fmaxf(sc[0][i], sc[1][i]), fmaxf(sc[2][i], sc[3][i]));
#pragma unroll
      for (int off = 1; off < 16; off <<= 1) mxi = fmaxf(mxi, __shfl_xor(mxi, off));
      float mnew = fmaxf(m_st[i], mxi);
      alpha[i] = __expf(m_st[i] - mnew);
      m_st[i] = mnew;
      float rsum = 0.f;
#pragma unroll
      for (int ct = 0; ct < 4; ++ct) { float pv = __expf(sc[ct][i] - mnew); p[ct][i] = pv; rsum += pv; }
#pragma unroll
      for (int off = 1; off < 16; off <<= 1) rsum += __shfl_xor(rsum, off);
      l_st[i] = l_st[i] * alpha[i] + rsum;
    }
    // ---- write P (fp16) + alpha to LDS ----
#pragma unroll
    for (int ct = 0; ct < 4; ++ct)
#pragma unroll
      for (int i = 0; i < 4; ++i)
        P_lds[(16 * w + 4 * quad + i) * 72 + 16 * ct + l16] = (_Float16)p[ct][i];
    if (l16 == 0)
#pragma unroll
      for (int i = 0; i < 4; ++i) alpha_lds[16 * w + 4 * quad + i] = alpha[i];
    __syncthreads();
    // ---- rescale O ----
#pragma unroll
    for (int rt = 0; rt < 4; ++rt)
#pragma unroll
      for (int i = 0; i < 4; ++i) {
        float a_r = alpha_lds[16 * rt + 4 * quad + i];
#pragma unroll
        for (int ct2 = 0; ct2 < 8; ++ct2) o[rt][ct2][i] *= a_r;
      }
    // ---- O += P @ Vt ----
    half8 pa[4][2];
#pragma unroll
    for (int rt = 0; rt < 4; ++rt)
#pragma unroll
      for (int s2 = 0; s2 < 2; ++s2)
        pa[rt][s2] = *(const half8*)&P_lds[(16 * rt + l16) * 72 + 32 * s2 + 8 * quad];
#pragma unroll
    for (int ct2 = 0; ct2 < 8; ++ct2) {
      int vv = 128 * w + 16 * ct2 + l16;
      half8 bv0 = *(const half8*)&vb[(size_t)vv * 4096 + m0 + 8 * quad];
      half8 bv1 = *(const half8*)&vb[(size_t)vv * 4096 + m0 + 32 + 8 * quad];
#pragma unroll
      for (int rt = 0; rt < 4; ++rt) {
        o[rt][ct2] = __builtin_amdgcn_mfma_f32_16x16x32_f16(pa[rt][0], bv0, o[rt][ct2], 0, 0, 0);
        o[rt][ct2] = __builtin_amdgcn_mfma_f32_16x16x32_f16(pa[rt][1], bv1, o[rt][ct2], 0, 0, 0);
      }
    }
    __syncthreads();
  }
  // ---- finalize ----
  if (l16 == 0)
#pragma unroll
    for (int i = 0; i < 4; ++i) l_lds[16 * w + 4 * quad + i] = l_st[i];
  __syncthreads();
  float* ob = out + (size_t)b * 512 * 4096;
#pragma unroll
  for (int rt = 0; rt < 4; ++rt)
#pragma unroll
    for (int i = 0; i < 4; ++i) {
      float inv_l = 1.0f / l_lds[16 * rt + 4 * quad + i];
      int n = n0 + 16 * rt + 4 * quad + i;
#pragma unroll
      for (int ct2 = 0; ct2 < 8; ++ct2) {
        int vv = 128 * w + 16 * ct2 + l16;
        ob[(size_t)vv * 4096 + n] = o[rt][ct2][i] * inv_l;
      }
    }
}

// ---------------- launch ----------------
extern "C" void kernel_launch(void* const* d_in, const int* in_sizes, int n_in,
                              void* d_out, int out_size, void* d_ws, size_t ws_size,
                              hipStream_t stream) {
  const float* x     = (const float*)d_in[0];
  const float* Wq    = (const float*)d_in[1];
  const float* bq    = (const float*)d_in[2];
  const float* Wk    = (const float*)d_in[3];
  const float* bk    = (const float*)d_in[4];
  const float* Wv    = (const float*)d_in[5];
  const float* gamma = (const float*)d_in[6];
  const float* beta  = (const float*)d_in[7];
  const float* mean  = (const float*)d_in[8];
  const float* var   = (const float*)d_in[9];
  float* out = (float*)d_out;

  char* ws = (char*)d_ws;
  _Float16* xT     = (_Float16*)(ws);                 // 33,554,432 B
  _Float16* W_all  = (_Float16*)(ws + 33554432);      //    655,360 B
  _Float16* q_buf  = (_Float16*)(ws + 34209792);      //  4,194,304 B
  _Float16* kT_buf = (_Float16*)(ws + 38404096);      //  4,194,304 B
  _Float16* v_buf  = (_Float16*)(ws + 42598400);      // 33,554,432 B -> total 76,152,832 B

  k_transpose<<<dim3(64, 8, 8), 256, 0, stream>>>(x, xT);
  k_wall<<<dim3(1280), 256, 0, stream>>>(Wq, Wk, Wv, W_all);
  k_proj<<<dim3(32, 5, 8), 256, 0, stream>>>(W_all, xT, bq, bk, gamma, beta, mean, var,
                                             q_buf, kT_buf, v_buf);
  k_flash<<<dim3(64, 8), 256, 0, stream>>>(q_buf, kT_buf, v_buf, out);
}

// Round 3
// 549.781 us; speedup vs baseline: 1.4200x; 1.4200x over previous
//
#include <hip/hip_runtime.h>

typedef __attribute__((ext_vector_type(8))) _Float16 half8;
typedef __attribute__((ext_vector_type(4))) float f32x4;

#define BN_EPS 1e-5f

__device__ __forceinline__ void async_copy16(const void* g, void* l) {
  __builtin_amdgcn_global_load_lds((const __attribute__((address_space(1))) void*)g,
                                   (__attribute__((address_space(3))) void*)l,
                                   16, 0, 0);
}

// ---------------- kernel 1: x (B,C,N) fp32 -> xT (B,N,C) fp16 ----------------
__global__ void k_transpose(const float* __restrict__ x, _Float16* __restrict__ xT) {
  __shared__ float tile[64][65];
  int n0 = blockIdx.x * 64, c0 = blockIdx.y * 64, b = blockIdx.z;
  const float* xb = x + (size_t)b * 512 * 4096;
  int t = threadIdx.x;
#pragma unroll
  for (int rep = 0; rep < 16; ++rep) {
    int idx = rep * 256 + t;
    int r = idx >> 6, cc = idx & 63;
    tile[r][cc] = xb[(size_t)(c0 + r) * 4096 + n0 + cc];
  }
  __syncthreads();
  _Float16* xTb = xT + (size_t)b * 4096 * 512;
#pragma unroll
  for (int rep = 0; rep < 16; ++rep) {
    int idx = rep * 256 + t;
    int r = idx >> 6, cc = idx & 63;
    xTb[(size_t)(n0 + r) * 512 + c0 + cc] = (_Float16)tile[cc][r];
  }
}

// ---------------- kernel 2: W_all (640x512) fp16 = [Wq; Wk; Wv] ----------------
__global__ void k_wall(const float* __restrict__ Wq, const float* __restrict__ Wk,
                       const float* __restrict__ Wv, _Float16* __restrict__ W_all) {
  int i = blockIdx.x * 256 + threadIdx.x;
  if (i >= 640 * 512) return;
  int m = i >> 9, c = i & 511;
  float v;
  if (m < 64) v = Wq[m * 512 + c];
  else if (m < 128) v = Wk[(m - 64) * 512 + c];
  else v = Wv[(m - 128) * 512 + c];
  W_all[i] = (_Float16)v;
}

// ---------------- kernel 3: proj GEMM: OUT(640 x 4096) = W_all @ x_b per batch ----------------
__global__ __launch_bounds__(256) void k_proj(
    const _Float16* __restrict__ W_all, const _Float16* __restrict__ xT,
    const float* __restrict__ bq, const float* __restrict__ bk,
    const float* __restrict__ gamma, const float* __restrict__ beta,
    const float* __restrict__ mean, const float* __restrict__ var,
    _Float16* __restrict__ q_buf, _Float16* __restrict__ kT_buf,
    _Float16* __restrict__ v_buf) {
  __shared__ __align__(16) _Float16 A_lds[128 * 32];
  __shared__ __align__(16) _Float16 B_lds[128 * 32];
  int nt = blockIdx.x, mt = blockIdx.y, b = blockIdx.z;
  int t = threadIdx.x, w = t >> 6, lane = t & 63;
  int quad = lane >> 4, l16 = lane & 15;
  int moff = (w & 1) * 64, noff = (w >> 1) * 64;

  f32x4 acc[4][4] = {};

  for (int kk = 0; kk < 16; ++kk) {
    int kc = kk * 32;
#pragma unroll
    for (int c = 0; c < 2; ++c) {
      int row = (w * 2 + c) * 16 + (lane >> 2);
      int kseg = (lane & 3) * 8;
      async_copy16(W_all + (size_t)(mt * 128 + row) * 512 + kc + kseg,
                   (char*)A_lds + (w * 2 + c) * 1024 + lane * 16);
      async_copy16(xT + ((size_t)b * 4096 + nt * 128 + row) * 512 + kc + kseg,
                   (char*)B_lds + (w * 2 + c) * 1024 + lane * 16);
    }
    __syncthreads();
    half8 a[4], bb[4];
#pragma unroll
    for (int mi = 0; mi < 4; ++mi)
      a[mi] = *(const half8*)&A_lds[(moff + 16 * mi + l16) * 32 + 8 * quad];
#pragma unroll
    for (int ni = 0; ni < 4; ++ni)
      bb[ni] = *(const half8*)&B_lds[(noff + 16 * ni + l16) * 32 + 8 * quad];
#pragma unroll
    for (int mi = 0; mi < 4; ++mi)
#pragma unroll
      for (int ni = 0; ni < 4; ++ni)
        acc[mi][ni] = __builtin_amdgcn_mfma_f32_16x16x32_f16(a[mi], bb[ni], acc[mi][ni], 0, 0, 0);
    __syncthreads();
  }

  size_t bN = (size_t)b * 4096;
#pragma unroll
  for (int mi = 0; mi < 4; ++mi) {
    int mbase = mt * 128 + moff + 16 * mi + 4 * quad;
#pragma unroll
    for (int ni = 0; ni < 4; ++ni) {
      int n = nt * 128 + noff + 16 * ni + l16;
#pragma unroll
      for (int i = 0; i < 4; ++i) {
        int m = mbase + i;
        float val = acc[mi][ni][i];
        if (m < 64) {
          q_buf[(bN + n) * 64 + m] = (_Float16)(val + bq[m]);
        } else if (m < 128) {
          kT_buf[(bN + n) * 64 + (m - 64)] = (_Float16)(val + bk[m - 64]);
        } else {
          int vv = m - 128;
          float sc = gamma[vv] * rsqrtf(var[vv] + BN_EPS);
          float sh = beta[vv] - mean[vv] * sc;
          float r = val * sc + sh;
          v_buf[((size_t)b * 512 + vv) * 4096 + n] = (_Float16)(r > 0.f ? r : 0.f);
        }
      }
    }
  }
}

// ---------------- kernel 4: flash attention ----------------
// per wg: batch b, 64 Q rows. wave w: S strip rows [16w,16w+16), O chunk V-cols [128w,128w+128)
// V prefetched one full iteration ahead into registers; single barrier/iter via
// double-buffered P/alpha LDS.
__global__ __launch_bounds__(256, 2) void k_flash(
    const _Float16* __restrict__ q_buf, const _Float16* __restrict__ kT_buf,
    const _Float16* __restrict__ v_buf, float* __restrict__ out) {
  __shared__ __align__(16) _Float16 P_lds[2][64 * 72];
  __shared__ __align__(16) float alpha_lds[2][64];
  __shared__ __align__(16) float l_lds[64];
  int b = blockIdx.y;
  int n0 = blockIdx.x * 64;
  int t = threadIdx.x, w = t >> 6, lane = t & 63, quad = lane >> 4, l16 = lane & 15;
  const _Float16* qb = q_buf + (size_t)b * 4096 * 64;
  // per-lane base pointers
  const _Float16* kp = kT_buf + (size_t)b * 4096 * 64 + l16 * 64 + 8 * quad;
  const _Float16* vp = v_buf + (size_t)b * 512 * 4096 + (size_t)(128 * w + l16) * 4096 + 8 * quad;

  half8 aq[2];
#pragma unroll
  for (int s = 0; s < 2; ++s)
    aq[s] = *(const half8*)&qb[(size_t)(n0 + 16 * w + l16) * 64 + 32 * s + 8 * quad];

  f32x4 o[4][8] = {};
  float m_st[4], l_st[4];
#pragma unroll
  for (int i = 0; i < 4; ++i) { m_st[i] = -1e30f; l_st[i] = 0.f; }

  // prefetch V(0) for iteration 0
  half8 vreg[16];
#pragma unroll
  for (int c2 = 0; c2 < 8; ++c2)
#pragma unroll
    for (int s = 0; s < 2; ++s)
      vreg[2 * c2 + s] = *(const half8*)&vp[c2 * 65536 + 32 * s];

#pragma unroll 1
  for (int it = 0; it < 64; ++it) {
    int m0 = it * 64;
    int mn = (it == 63) ? 0 : m0 + 64;  // next-iter base (wraps harmlessly)
    _Float16* Pb = P_lds[it & 1];
    float* Ab = alpha_lds[it & 1];

    // ---- S = Q Kt for this wave's 16-row strip (K loads inline, 4 indep chains) ----
    f32x4 sc[4];
#pragma unroll
    for (int ct = 0; ct < 4; ++ct) {
      half8 k0 = *(const half8*)&kp[m0 * 64 + ct * 1024];
      half8 k1 = *(const half8*)&kp[m0 * 64 + ct * 1024 + 32];
      f32x4 sa = {0.f, 0.f, 0.f, 0.f};
      sa = __builtin_amdgcn_mfma_f32_16x16x32_f16(aq[0], k0, sa, 0, 0, 0);
      sa = __builtin_amdgcn_mfma_f32_16x16x32_f16(aq[1], k1, sa, 0, 0, 0);
      sc[ct] = sa;
    }

    // ---- online softmax (rows 4*quad+i of strip); write P + alpha to buf[it&1] ----
#pragma unroll
    for (int i = 0; i < 4; ++i) {
      float mxi = fmaxf(fmaxf(sc[0][i], sc[1][i]), fmaxf(sc[2][i], sc[3][i]));
#pragma unroll
      for (int off = 1; off < 16; off <<= 1) mxi = fmaxf(mxi, __shfl_xor(mxi, off));
      float mnew = fmaxf(m_st[i], mxi);
      float alpha_i = __expf(m_st[i] - mnew);
      m_st[i] = mnew;
      float rsum = 0.f;
#pragma unroll
      for (int ct = 0; ct < 4; ++ct) {
        float pv = __expf(sc[ct][i] - mnew);
        Pb[(16 * w + 4 * quad + i) * 72 + 16 * ct + l16] = (_Float16)pv;
        rsum += pv;
      }
#pragma unroll
      for (int off = 1; off < 16; off <<= 1) rsum += __shfl_xor(rsum, off);
      l_st[i] = l_st[i] * alpha_i + rsum;
      if (l16 == 0) Ab[16 * w + 4 * quad + i] = alpha_i;
    }
    __syncthreads();

    // ---- rescale O (vectorized alpha broadcast) ----
#pragma unroll
    for (int rt = 0; rt < 4; ++rt) {
      f32x4 ar = *(const f32x4*)&Ab[16 * rt + 4 * quad];
#pragma unroll
      for (int c2 = 0; c2 < 8; ++c2)
#pragma unroll
        for (int i = 0; i < 4; ++i) o[rt][c2][i] *= ar[i];
    }

    // ---- O += P @ Vt ; reload vreg for next iter as each pair is consumed ----
    half8 pa0[4], pa1[4];
#pragma unroll
    for (int rt = 0; rt < 4; ++rt) {
      pa0[rt] = *(const half8*)&Pb[(16 * rt + l16) * 72 + 8 * quad];
      pa1[rt] = *(const half8*)&Pb[(16 * rt + l16) * 72 + 32 + 8 * quad];
    }
#pragma unroll
    for (int c2 = 0; c2 < 8; ++c2) {
      half8 bv0 = vreg[2 * c2], bv1 = vreg[2 * c2 + 1];
#pragma unroll
      for (int rt = 0; rt < 4; ++rt) {
        o[rt][c2] = __builtin_amdgcn_mfma_f32_16x16x32_f16(pa0[rt], bv0, o[rt][c2], 0, 0, 0);
        o[rt][c2] = __builtin_amdgcn_mfma_f32_16x16x32_f16(pa1[rt], bv1, o[rt][c2], 0, 0, 0);
      }
      vreg[2 * c2]     = *(const half8*)&vp[c2 * 65536 + mn];
      vreg[2 * c2 + 1] = *(const half8*)&vp[c2 * 65536 + mn + 32];
    }
  }

  // ---- finalize ----
  if (l16 == 0)
#pragma unroll
    for (int i = 0; i < 4; ++i) l_lds[16 * w + 4 * quad + i] = l_st[i];
  __syncthreads();
  float* ob = out + (size_t)b * 512 * 4096;
#pragma unroll
  for (int rt = 0; rt < 4; ++rt) {
    f32x4 lv = *(const f32x4*)&l_lds[16 * rt + 4 * quad];
#pragma unroll
    for (int i = 0; i < 4; ++i) {
      float inv_l = 1.0f / lv[i];
      int n = n0 + 16 * rt + 4 * quad + i;
#pragma unroll
      for (int c2 = 0; c2 < 8; ++c2) {
        int vv = 128 * w + 16 * c2 + l16;
        ob[(size_t)vv * 4096 + n] = o[rt][c2][i] * inv_l;
      }
    }
  }
}

// ---------------- launch ----------------
extern "C" void kernel_launch(void* const* d_in, const int* in_sizes, int n_in,
                              void* d_out, int out_size, void* d_ws, size_t ws_size,
                              hipStream_t stream) {
  const float* x     = (const float*)d_in[0];
  const float* Wq    = (const float*)d_in[1];
  const float* bq    = (const float*)d_in[2];
  const float* Wk    = (const float*)d_in[3];
  const float* bk    = (const float*)d_in[4];
  const float* Wv    = (const float*)d_in[5];
  const float* gamma = (const float*)d_in[6];
  const float* beta  = (const float*)d_in[7];
  const float* mean  = (const float*)d_in[8];
  const float* var   = (const float*)d_in[9];
  float* out = (float*)d_out;

  char* ws = (char*)d_ws;
  _Float16* xT     = (_Float16*)(ws);                 // 33,554,432 B
  _Float16* W_all  = (_Float16*)(ws + 33554432);      //    655,360 B
  _Float16* q_buf  = (_Float16*)(ws + 34209792);      //  4,194,304 B
  _Float16* kT_buf = (_Float16*)(ws + 38404096);      //  4,194,304 B
  _Float16* v_buf  = (_Float16*)(ws + 42598400);      // 33,554,432 B -> total 76,152,832 B

  k_transpose<<<dim3(64, 8, 8), 256, 0, stream>>>(x, xT);
  k_wall<<<dim3(1280), 256, 0, stream>>>(Wq, Wk, Wv, W_all);
  k_proj<<<dim3(32, 5, 8), 256, 0, stream>>>(W_all, xT, bq, bk, gamma, beta, mean, var,
                                             q_buf, kT_buf, v_buf);
  k_flash<<<dim3(64, 8), 256, 0, stream>>>(q_buf, kT_buf, v_buf, out);
}

// Round 4
// 460.456 us; speedup vs baseline: 1.6955x; 1.1940x over previous
//
#include <hip/hip_runtime.h>

typedef __attribute__((ext_vector_type(8))) _Float16 half8;
typedef __attribute__((ext_vector_type(4))) float f32x4;

#define BN_EPS 1e-5f

__device__ __forceinline__ void async_copy16(const void* g, void* l) {
  __builtin_amdgcn_global_load_lds((const __attribute__((address_space(1))) void*)g,
                                   (__attribute__((address_space(3))) void*)l,
                                   16, 0, 0);
}

// ---------------- kernel 1: x (B,C,N) fp32 -> xT (B,N,C) fp16 ----------------
__global__ void k_transpose(const float* __restrict__ x, _Float16* __restrict__ xT) {
  __shared__ float tile[64][65];
  int n0 = blockIdx.x * 64, c0 = blockIdx.y * 64, b = blockIdx.z;
  const float* xb = x + (size_t)b * 512 * 4096;
  int t = threadIdx.x;
#pragma unroll
  for (int rep = 0; rep < 16; ++rep) {
    int idx = rep * 256 + t;
    int r = idx >> 6, cc = idx & 63;
    tile[r][cc] = xb[(size_t)(c0 + r) * 4096 + n0 + cc];
  }
  __syncthreads();
  _Float16* xTb = xT + (size_t)b * 4096 * 512;
#pragma unroll
  for (int rep = 0; rep < 16; ++rep) {
    int idx = rep * 256 + t;
    int r = idx >> 6, cc = idx & 63;
    xTb[(size_t)(n0 + r) * 512 + c0 + cc] = (_Float16)tile[cc][r];
  }
}

// ---------------- kernel 2: W_all (640x512) fp16 = [Wq; Wk; Wv] ----------------
__global__ void k_wall(const float* __restrict__ Wq, const float* __restrict__ Wk,
                       const float* __restrict__ Wv, _Float16* __restrict__ W_all) {
  int i = blockIdx.x * 256 + threadIdx.x;
  if (i >= 640 * 512) return;
  int m = i >> 9, c = i & 511;
  float v;
  if (m < 64) v = Wq[m * 512 + c];
  else if (m < 128) v = Wk[(m - 64) * 512 + c];
  else v = Wv[(m - 128) * 512 + c];
  W_all[i] = (_Float16)v;
}

// ---------------- kernel 3: proj GEMM ----------------
__global__ __launch_bounds__(256) void k_proj(
    const _Float16* __restrict__ W_all, const _Float16* __restrict__ xT,
    const float* __restrict__ bq, const float* __restrict__ bk,
    const float* __restrict__ gamma, const float* __restrict__ beta,
    const float* __restrict__ mean, const float* __restrict__ var,
    _Float16* __restrict__ q_buf, _Float16* __restrict__ kT_buf,
    _Float16* __restrict__ v_buf) {
  __shared__ __align__(16) _Float16 A_lds[128 * 32];
  __shared__ __align__(16) _Float16 B_lds[128 * 32];
  int nt = blockIdx.x, mt = blockIdx.y, b = blockIdx.z;
  int t = threadIdx.x, w = t >> 6, lane = t & 63;
  int quad = lane >> 4, l16 = lane & 15;
  int moff = (w & 1) * 64, noff = (w >> 1) * 64;

  f32x4 acc[4][4] = {};

  for (int kk = 0; kk < 16; ++kk) {
    int kc = kk * 32;
#pragma unroll
    for (int c = 0; c < 2; ++c) {
      int row = (w * 2 + c) * 16 + (lane >> 2);
      int kseg = (lane & 3) * 8;
      async_copy16(W_all + (size_t)(mt * 128 + row) * 512 + kc + kseg,
                   (char*)A_lds + (w * 2 + c) * 1024 + lane * 16);
      async_copy16(xT + ((size_t)b * 4096 + nt * 128 + row) * 512 + kc + kseg,
                   (char*)B_lds + (w * 2 + c) * 1024 + lane * 16);
    }
    __syncthreads();
    half8 a[4], bb[4];
#pragma unroll
    for (int mi = 0; mi < 4; ++mi)
      a[mi] = *(const half8*)&A_lds[(moff + 16 * mi + l16) * 32 + 8 * quad];
#pragma unroll
    for (int ni = 0; ni < 4; ++ni)
      bb[ni] = *(const half8*)&B_lds[(noff + 16 * ni + l16) * 32 + 8 * quad];
#pragma unroll
    for (int mi = 0; mi < 4; ++mi)
#pragma unroll
      for (int ni = 0; ni < 4; ++ni)
        acc[mi][ni] = __builtin_amdgcn_mfma_f32_16x16x32_f16(a[mi], bb[ni], acc[mi][ni], 0, 0, 0);
    __syncthreads();
  }

  size_t bN = (size_t)b * 4096;
#pragma unroll
  for (int mi = 0; mi < 4; ++mi) {
    int mbase = mt * 128 + moff + 16 * mi + 4 * quad;
#pragma unroll
    for (int ni = 0; ni < 4; ++ni) {
      int n = nt * 128 + noff + 16 * ni + l16;
#pragma unroll
      for (int i = 0; i < 4; ++i) {
        int m = mbase + i;
        float val = acc[mi][ni][i];
        if (m < 64) {
          q_buf[(bN + n) * 64 + m] = (_Float16)(val + bq[m]);
        } else if (m < 128) {
          kT_buf[(bN + n) * 64 + (m - 64)] = (_Float16)(val + bk[m - 64]);
        } else {
          int vv = m - 128;
          float sc = gamma[vv] * rsqrtf(var[vv] + BN_EPS);
          float sh = beta[vv] - mean[vv] * sc;
          float r = val * sc + sh;
          v_buf[((size_t)b * 512 + vv) * 4096 + n] = (_Float16)(r > 0.f ? r : 0.f);
        }
      }
    }
  }
}

// ---------------- kernel 4: flash attention ----------------
// 512 threads / 8 waves; WG: batch b = blockIdx.x&7 (XCD affinity), 128 Q rows.
// wave w: S strip rows [16w,16w+16), O chunk V-cols [64w,64w+64) x 128 Q rows.
// K tile: async global_load_lds, XOR-swizzled, double-buffered (shared by all waves).
// V: register prefetch one iteration ahead. Single barrier/iter (dbuf P/alpha).
__global__ __launch_bounds__(512, 2) void k_flash(
    const _Float16* __restrict__ q_buf, const _Float16* __restrict__ kT_buf,
    const _Float16* __restrict__ v_buf, float* __restrict__ out) {
  __shared__ __align__(16) _Float16 P_lds[2][128 * 72];
  __shared__ __align__(16) _Float16 K_lds[2][64 * 64];
  __shared__ __align__(16) float alpha_lds[2][128];
  __shared__ __align__(16) float l_lds[128];
  int b = blockIdx.x & 7;
  int n0 = (blockIdx.x >> 3) * 128;
  int t = threadIdx.x, w = t >> 6, lane = t & 63, quad = lane >> 4, l16 = lane & 15;
  const _Float16* qb = q_buf + (size_t)b * 4096 * 64;
  const char* kbb = (const char*)(kT_buf + (size_t)b * 4096 * 64);
  const _Float16* vp = v_buf + (size_t)b * 512 * 4096 + (size_t)(64 * w + l16) * 4096 + 8 * quad;

  // K staging source address pieces (lane-fixed): LDS row r, swizzled source block
  int st_r = w * 8 + (lane >> 3);                  // tile row this lane stages
  int st_c = (lane & 7) ^ (st_r & 7);              // source 16B block (XOR swizzle)
  int st_dst = w * 1024 + lane * 16;               // LDS byte offset (wave-uniform base + lane*16)
  int st_src = st_r * 128 + st_c * 16;             // byte offset within K tile

  half8 aq[2];
#pragma unroll
  for (int s = 0; s < 2; ++s)
    aq[s] = *(const half8*)&qb[(size_t)(n0 + 16 * w + l16) * 64 + 32 * s + 8 * quad];

  f32x4 o[8][4] = {};
  float m_st[4], l_st[4];
#pragma unroll
  for (int i = 0; i < 4; ++i) { m_st[i] = -1e30f; l_st[i] = 0.f; }

  // prefetch V(0); stage K(0) into buf 0
  half8 vreg[8];
#pragma unroll
  for (int c2 = 0; c2 < 4; ++c2)
#pragma unroll
    for (int s = 0; s < 2; ++s)
      vreg[2 * c2 + s] = *(const half8*)&vp[c2 * 65536 + 32 * s];
  async_copy16(kbb + st_src, (char*)K_lds[0] + st_dst);
  __syncthreads();

#pragma unroll 1
  for (int it = 0; it < 64; ++it) {
    int m0 = it * 64;
    int mn = (it == 63) ? 0 : m0 + 64;  // next-iter base (wrap harmless)
    _Float16* Pb = P_lds[it & 1];
    float* Ab = alpha_lds[it & 1];
    const _Float16* Kb = K_lds[it & 1];

    // stage K(t+1) into the other buffer (completes by the barrier below)
    async_copy16(kbb + mn * 128 + st_src, (char*)K_lds[(it + 1) & 1] + st_dst);

    // ---- S = Q Kt for this wave's 16-row strip (K frags from swizzled LDS) ----
    f32x4 sc[4];
#pragma unroll
    for (int ct = 0; ct < 4; ++ct) {
      int row = 16 * ct + l16;
      int sw = (row & 7) * 16;
      half8 k0 = *(const half8*)((const char*)Kb + row * 128 + ((quad * 16) ^ sw));
      half8 k1 = *(const half8*)((const char*)Kb + row * 128 + (((4 + quad) * 16) ^ sw));
      f32x4 sa = {0.f, 0.f, 0.f, 0.f};
      sa = __builtin_amdgcn_mfma_f32_16x16x32_f16(aq[0], k0, sa, 0, 0, 0);
      sa = __builtin_amdgcn_mfma_f32_16x16x32_f16(aq[1], k1, sa, 0, 0, 0);
      sc[ct] = sa;
    }

    // ---- online softmax; per-lane partial l; write P + alpha ----
#pragma unroll
    for (int i = 0; i < 4; ++i) {
      float mxi = fmaxf(fmaxf(sc[0][i], sc[1][i]), fmaxf(sc[2][i], sc[3][i]));
#pragma unroll
      for (int off = 1; off < 16; off <<= 1) mxi = fmaxf(mxi, __shfl_xor(mxi, off));
      float mnew = fmaxf(m_st[i], mxi);
      float alpha_i = __expf(m_st[i] - mnew);
      m_st[i] = mnew;
      float rsum = 0.f;
#pragma unroll
      for (int ct = 0; ct < 4; ++ct) {
        float pv = __expf(sc[ct][i] - mnew);
        Pb[(16 * w + 4 * quad + i) * 72 + 16 * ct + l16] = (_Float16)pv;
        rsum += pv;
      }
      l_st[i] = l_st[i] * alpha_i + rsum;   // per-lane partial (reduced at end)
      if (l16 == 0) Ab[16 * w + 4 * quad + i] = alpha_i;
    }
    __syncthreads();

    // ---- rescale O (skip row-tiles whose alphas are all 1) ----
#pragma unroll
    for (int rt = 0; rt < 8; ++rt) {
      f32x4 ar = *(const f32x4*)&Ab[16 * rt + 4 * quad];
      bool nd = (ar[0] != 1.f) | (ar[1] != 1.f) | (ar[2] != 1.f) | (ar[3] != 1.f);
      if (__any(nd)) {
#pragma unroll
        for (int c2 = 0; c2 < 4; ++c2)
#pragma unroll
          for (int i = 0; i < 4; ++i) o[rt][c2][i] *= ar[i];
      }
    }

    // ---- O += P @ Vt ; reload vreg for next iter ----
#pragma unroll
    for (int rt = 0; rt < 8; ++rt) {
      half8 pa0 = *(const half8*)&Pb[(16 * rt + l16) * 72 + 8 * quad];
      half8 pa1 = *(const half8*)&Pb[(16 * rt + l16) * 72 + 32 + 8 * quad];
#pragma unroll
      for (int c2 = 0; c2 < 4; ++c2) {
        o[rt][c2] = __builtin_amdgcn_mfma_f32_16x16x32_f16(pa0, vreg[2 * c2], o[rt][c2], 0, 0, 0);
        o[rt][c2] = __builtin_amdgcn_mfma_f32_16x16x32_f16(pa1, vreg[2 * c2 + 1], o[rt][c2], 0, 0, 0);
      }
    }
#pragma unroll
    for (int c2 = 0; c2 < 4; ++c2) {
      vreg[2 * c2]     = *(const half8*)&vp[c2 * 65536 + mn];
      vreg[2 * c2 + 1] = *(const half8*)&vp[c2 * 65536 + mn + 32];
    }
  }

  // ---- finalize: reduce per-lane l partials across the 16 lanes of each row ----
#pragma unroll
  for (int i = 0; i < 4; ++i) {
    float s = l_st[i];
#pragma unroll
    for (int off = 1; off < 16; off <<= 1) s += __shfl_xor(s, off);
    if (l16 == 0) l_lds[16 * w + 4 * quad + i] = s;
  }
  __syncthreads();
  float* ob = out + (size_t)b * 512 * 4096;
#pragma unroll
  for (int rt = 0; rt < 8; ++rt) {
    f32x4 lv = *(const f32x4*)&l_lds[16 * rt + 4 * quad];
    f32x4 inv;
#pragma unroll
    for (int i = 0; i < 4; ++i) inv[i] = 1.0f / lv[i];
#pragma unroll
    for (int c2 = 0; c2 < 4; ++c2) {
      int vv = 64 * w + 16 * c2 + l16;
      f32x4 res = o[rt][c2] * inv;
      *(f32x4*)(ob + (size_t)vv * 4096 + n0 + 16 * rt + 4 * quad) = res;
    }
  }
}

// ---------------- launch ----------------
extern "C" void kernel_launch(void* const* d_in, const int* in_sizes, int n_in,
                              void* d_out, int out_size, void* d_ws, size_t ws_size,
                              hipStream_t stream) {
  const float* x     = (const float*)d_in[0];
  const float* Wq    = (const float*)d_in[1];
  const float* bq    = (const float*)d_in[2];
  const float* Wk    = (const float*)d_in[3];
  const float* bk    = (const float*)d_in[4];
  const float* Wv    = (const float*)d_in[5];
  const float* gamma = (const float*)d_in[6];
  const float* beta  = (const float*)d_in[7];
  const float* mean  = (const float*)d_in[8];
  const float* var   = (const float*)d_in[9];
  float* out = (float*)d_out;

  char* ws = (char*)d_ws;
  _Float16* xT     = (_Float16*)(ws);                 // 33,554,432 B
  _Float16* W_all  = (_Float16*)(ws + 33554432);      //    655,360 B
  _Float16* q_buf  = (_Float16*)(ws + 34209792);      //  4,194,304 B
  _Float16* kT_buf = (_Float16*)(ws + 38404096);      //  4,194,304 B
  _Float16* v_buf  = (_Float16*)(ws + 42598400);      // 33,554,432 B -> total 76,152,832 B

  k_transpose<<<dim3(64, 8, 8), 256, 0, stream>>>(x, xT);
  k_wall<<<dim3(1280), 256, 0, stream>>>(Wq, Wk, Wv, W_all);
  k_proj<<<dim3(32, 5, 8), 256, 0, stream>>>(W_all, xT, bq, bk, gamma, beta, mean, var,
                                             q_buf, kT_buf, v_buf);
  k_flash<<<dim3(256), 512, 0, stream>>>(q_buf, kT_buf, v_buf, out);
}